// Round 20
// baseline (54.783 us; speedup 1.0000x reference)
//
#include <hip/hip_runtime.h>

typedef unsigned short UST;
typedef __attribute__((ext_vector_type(8))) __bf16 bf16x8;
typedef __attribute__((ext_vector_type(4))) float f32x4;
typedef __attribute__((ext_vector_type(16))) float f32x16;

#define NB 4
#define NH 8
#define LSEQ 1024
#define DMODEL 512
#define DH 64

__device__ __forceinline__ UST f2bf(float f) {
  union { float f; unsigned u; } v; v.f = f;
  unsigned u = v.u;
  return (UST)((u + 0x7FFFu + ((u >> 16) & 1u)) >> 16);
}
__device__ __forceinline__ float bf2f(UST h) {
  union { unsigned u; float f; } v; v.u = ((unsigned)h) << 16;
  return v.f;
}
__device__ __forceinline__ unsigned cvt_pk_bf16(float lo, float hi) {
  unsigned r;
  asm volatile("v_cvt_pk_bf16_f32 %0, %1, %2" : "=v"(r) : "v"(lo), "v"(hi));
  return r;
}

// ---------------- kernel 1: fused setup ----------------
// blocks 0..2047:    x fp32 -> bf16 (R17-verified path)
// blocks 2048..2175: beta fill of kext cols 64..127 — DEDUPED: each (l, j) pair's
//                    sin/cos computed ONCE (32K transcendentals, was 1M) and the
//                    32 identical bh copies written in a loop (same expressions,
//                    same f2bf rounding -> bit-identical kext values).
// blocks 2176..2367: W transpose -> WT bf16 (R17-verified path, 24x8 tiles)
__global__ void k_setup(const float* __restrict__ x, UST* __restrict__ xbf,
                        UST* __restrict__ kext,
                        const float* __restrict__ W, UST* __restrict__ WT) {
  __shared__ float tile[64][65];
  int bid = blockIdx.x;
  if (bid < 2048) {
    int i = bid * 256 + threadIdx.x;   // 2097152/4 elements
    float4 v = ((const float4*)x)[i];
    ushort4 o;
    o.x = f2bf(v.x); o.y = f2bf(v.y); o.z = f2bf(v.z); o.w = f2bf(v.w);
    ((ushort4*)xbf)[i] = o;
  } else if (bid < 2176) {
    int gid = (bid - 2048) * 256 + threadIdx.x;  // 1024*32 (l, j) pairs
    int j = gid & 31;
    int l = gid >> 5;
    float dd = exp2f((float)(-2 * j) * 0.20762050593046f);
    float ang = (float)l * dd;
    float s = __sinf(ang), c = __cosf(ang);
    UST cv = f2bf(c), sv = f2bf(s);
    UST* kp = kext + (size_t)l * 128;
#pragma unroll
    for (int bh = 0; bh < 32; ++bh) {
      kp[64 + j] = cv;
      kp[96 + j] = sv;
      kp += (size_t)1024 * 128;
    }
  } else {
    int tid = bid - 2176;               // 0..191 = 24 x 8 tiles
    int n0 = (tid % 24) * 64;           // over 1536
    int k0 = (tid / 24) * 64;           // over 512
    int tx = threadIdx.x & 63, ty = threadIdx.x >> 6;  // ty 0..3
#pragma unroll
    for (int i = 0; i < 16; ++i) {
      int k = ty + i * 4;
      tile[k][tx] = W[(size_t)(k0 + k) * 1536 + n0 + tx];
    }
    __syncthreads();
#pragma unroll
    for (int i = 0; i < 16; ++i) {
      int n = ty + i * 4;
      WT[(size_t)(n0 + n) * 512 + k0 + tx] = f2bf(tile[tx][n]);
    }
  }
}

// ---------------- kernel 3: projection GEMM + scatter + fused alpha (R17) ----------
__global__ __launch_bounds__(256) void k_proj(
    const UST* __restrict__ xbf, const UST* __restrict__ WT, const float* __restrict__ bias,
    UST* __restrict__ qext, UST* __restrict__ kext, UST* __restrict__ vT) {
  int m0 = blockIdx.x * 128;  // token tile
  int n0 = blockIdx.y * 64;   // out-col tile
  int t = threadIdx.x;
  int lane = t & 63, w = t >> 6;
  int wr = w >> 1, wc = w & 1;
  int g = lane >> 4, c16 = lane & 15;

  __shared__ UST AtS[2][128 * 64];  // 2 x 16KB
  __shared__ UST BtS[2][64 * 64];   // 2 x 8KB

  const char* Ag = (const char*)(xbf + (size_t)m0 * 512);  // row stride 1024B
  const char* Bg = (const char*)(WT + (size_t)n0 * 512);   // row stride 1024B

  bf16x8 areg[4], breg[2];
#pragma unroll
  for (int c = 0; c < 4; ++c) {
    int u = c * 256 + t, r = u >> 3, s = u & 7;
    areg[c] = *(const bf16x8*)(Ag + (size_t)r * 1024 + s * 16);
  }
#pragma unroll
  for (int c = 0; c < 2; ++c) {
    int u = c * 256 + t, r = u >> 3, s = u & 7;
    breg[c] = *(const bf16x8*)(Bg + (size_t)r * 1024 + s * 16);
  }
#pragma unroll
  for (int c = 0; c < 4; ++c) {
    int u = c * 256 + t, r = u >> 3, s = u & 7;
    *(bf16x8*)((char*)AtS[0] + (size_t)r * 128 + (s ^ (r & 7)) * 16) = areg[c];
  }
#pragma unroll
  for (int c = 0; c < 2; ++c) {
    int u = c * 256 + t, r = u >> 3, s = u & 7;
    *(bf16x8*)((char*)BtS[0] + (size_t)r * 128 + (s ^ (r & 7)) * 16) = breg[c];
  }
#pragma unroll
  for (int c = 0; c < 4; ++c) {
    int u = c * 256 + t, r = u >> 3, s = u & 7;
    areg[c] = *(const bf16x8*)(Ag + (size_t)r * 1024 + 128 + s * 16);
  }
#pragma unroll
  for (int c = 0; c < 2; ++c) {
    int u = c * 256 + t, r = u >> 3, s = u & 7;
    breg[c] = *(const bf16x8*)(Bg + (size_t)r * 1024 + 128 + s * 16);
  }
  __syncthreads();

  f32x4 acc[4][2] = {};
  for (int it = 0; it < 8; ++it) {
    int cur = it & 1;
    const char* Ab = (const char*)(AtS[cur]);
    const char* Bb = (const char*)(BtS[cur]);

#pragma unroll
    for (int kf = 0; kf < 2; ++kf) {
      bf16x8 af[4], bfr[2];
#pragma unroll
      for (int rf = 0; rf < 4; ++rf) {
        int r = wr * 64 + rf * 16 + c16;
        int s = (kf * 4 + g) ^ (r & 7);
        af[rf] = *(const bf16x8*)(Ab + (size_t)r * 128 + s * 16);
      }
#pragma unroll
      for (int cf = 0; cf < 2; ++cf) {
        int r = wc * 32 + cf * 16 + c16;
        int s = (kf * 4 + g) ^ (r & 7);
        bfr[cf] = *(const bf16x8*)(Bb + (size_t)r * 128 + s * 16);
      }
      __builtin_amdgcn_s_setprio(1);
#pragma unroll
      for (int rf = 0; rf < 4; ++rf)
#pragma unroll
        for (int cf = 0; cf < 2; ++cf)
          acc[rf][cf] = __builtin_amdgcn_mfma_f32_16x16x32_bf16(af[rf], bfr[cf], acc[rf][cf], 0, 0, 0);
      __builtin_amdgcn_s_setprio(0);
    }

    if (it < 7) {
      char* Aw = (char*)(AtS[cur ^ 1]);
      char* Bw = (char*)(BtS[cur ^ 1]);
#pragma unroll
      for (int c = 0; c < 4; ++c) {
        int u = c * 256 + t, r = u >> 3, s = u & 7;
        *(bf16x8*)(Aw + (size_t)r * 128 + (s ^ (r & 7)) * 16) = areg[c];
      }
#pragma unroll
      for (int c = 0; c < 2; ++c) {
        int u = c * 256 + t, r = u >> 3, s = u & 7;
        *(bf16x8*)(Bw + (size_t)r * 128 + (s ^ (r & 7)) * 16) = breg[c];
      }
      if (it < 6) {
        size_t cb = (size_t)(it + 2) * 128;
#pragma unroll
        for (int c = 0; c < 4; ++c) {
          int u = c * 256 + t, r = u >> 3, s = u & 7;
          areg[c] = *(const bf16x8*)(Ag + (size_t)r * 1024 + cb + s * 16);
        }
#pragma unroll
        for (int c = 0; c < 2; ++c) {
          int u = c * 256 + t, r = u >> 3, s = u & 7;
          breg[c] = *(const bf16x8*)(Bg + (size_t)r * 1024 + cb + s * 16);
        }
      }
    }
    __syncthreads();
  }

  bool doalpha = (blockIdx.y % 3 == 0);   // block-uniform
  UST* stash = AtS[0];

#pragma unroll
  for (int rf = 0; rf < 4; ++rf) {
#pragma unroll
    for (int cf = 0; cf < 2; ++cf) {
      int c = n0 + wc * 32 + cf * 16 + c16;
      int h = c / 192, rem = c % 192;
      float bv = bias[c];
#pragma unroll
      for (int r = 0; r < 4; ++r) {
        int row = m0 + wr * 64 + rf * 16 + g * 4 + r;
        int bidx = row >> 10, ltok = row & 1023;
        int bh = bidx * 8 + h;
        float val = acc[rf][cf][r] + bv;
        if (rem < 64) {
          UST qv = f2bf(val * 0.125f);
          qext[((size_t)bh * 1024 + ltok) * 128 + rem] = qv;
          if (doalpha)
            stash[(size_t)(row - m0) * 64 + rem] = qv;
        } else if (rem < 128)
          kext[((size_t)bh * 1024 + ltok) * 128 + (rem - 64)] = f2bf(val);
        else
          vT[((size_t)bh * 64 + (rem - 128)) * 1024 + ltok] = f2bf(val);
      }
    }
  }

  if (doalpha) {
    __syncthreads();
    int hh = blockIdx.y / 3;
    int rr = t >> 1;
    int row = m0 + rr;
    int bidx = row >> 10, ltok = row & 1023;
    int bh = bidx * 8 + hh;
    UST* qp = qext + ((size_t)bh * 1024 + ltok) * 128;
#pragma unroll
    for (int i = 0; i < 16; ++i) {
      int j = (t & 1) * 16 + i;
      float dd = exp2f((float)(-2 * j) * 0.20762050593046f);
      float ang = (float)ltok * dd;
      float s = __sinf(ang), c = __cosf(ang);
      float qs = bf2f(stash[(size_t)rr * 64 + j]);
      float qc = bf2f(stash[(size_t)rr * 64 + 32 + j]);
      qp[64 + j] = f2bf(qs * s + qc * c);
      qp[96 + j] = f2bf(qc * s - qs * c);
    }
  }
}

// ---------------- kernel 5: fused flash attention (R17/R19-verified, unchanged) ------
__global__ __launch_bounds__(256) void k_attn(
    const UST* __restrict__ qext, const UST* __restrict__ kext,
    const UST* __restrict__ vT, float* __restrict__ out) {
  int blk = ((blockIdx.x & 7) << 6) | (blockIdx.x >> 3);  // XCD-contiguous bh ranges
  int qt = blk & 15, bh = blk >> 4;
  int b = bh >> 3, h = bh & 7;
  int q0 = qt * 64;
  int t = threadIdx.x;
  int lane = t & 63, w = t >> 6;
  int l31 = lane & 31, lh = lane >> 5;
  int wq = w >> 1, wk = w & 1;

  __shared__ UST KtS[2][64 * 128];   // 2 x 16KB
  __shared__ UST VtS[2][64 * 64];    // 2 x 8KB
  __shared__ float Lsum[2][2][32];   // [wk][wq][row]

  const UST* qbase = qext + ((size_t)bh * 1024 + q0 + wq * 32 + l31) * 128 + lh * 8;
  bf16x8 qf[8];
#pragma unroll
  for (int c = 0; c < 8; ++c) qf[c] = *(const bf16x8*)&qbase[c * 16];

  const char* kgbase = (const char*)(kext + (size_t)bh * 1024 * 128);
  const char* vgbase = (const char*)(vT + (size_t)bh * 64 * 1024);

  f32x16 O[2] = {};
  float l_lane = 0.f;

  bf16x8 kreg[4], vreg[2];
#pragma unroll
  for (int c = 0; c < 4; ++c) {
    int u = c * 256 + t;
    kreg[c] = *(const bf16x8*)(kgbase + (size_t)(u >> 4) * 256 + (u & 15) * 16);
  }
#pragma unroll
  for (int c = 0; c < 2; ++c) {
    int u = c * 256 + t;
    vreg[c] = *(const bf16x8*)(vgbase + (size_t)(u >> 3) * 2048 + (u & 7) * 16);
  }
#pragma unroll
  for (int c = 0; c < 4; ++c) {
    int u = c * 256 + t, r = u >> 4, s = u & 15;
    *(bf16x8*)((char*)KtS[0] + (size_t)r * 256 + (s ^ ((r ^ (r >> 3)) & 7)) * 16) = kreg[c];
  }
#pragma unroll
  for (int c = 0; c < 2; ++c) {
    int u = c * 256 + t, r = u >> 3, s = u & 7;
    *(bf16x8*)((char*)VtS[0] + (size_t)r * 128 + (s ^ ((r ^ (r >> 3)) & 7)) * 16) = vreg[c];
  }
#pragma unroll
  for (int c = 0; c < 4; ++c) {
    int u = c * 256 + t;
    kreg[c] = *(const bf16x8*)(kgbase + 64 * 256 + (size_t)(u >> 4) * 256 + (u & 15) * 16);
  }
#pragma unroll
  for (int c = 0; c < 2; ++c) {
    int u = c * 256 + t;
    vreg[c] = *(const bf16x8*)(vgbase + 64 * 2 + (size_t)(u >> 3) * 2048 + (u & 7) * 16);
  }
  __syncthreads();

  int krow = wk * 32 + l31;
  int ksalt = (krow ^ (krow >> 3)) & 7;

  for (int it = 0; it < 16; ++it) {
    int cur = it & 1;
    const char* Kb = (const char*)(KtS[cur]);
    const char* Vb = (const char*)(VtS[cur]);

    f32x16 sa = {};
#pragma unroll
    for (int kh = 0; kh < 2; ++kh) {
      bf16x8 kfr[4];
#pragma unroll
      for (int kc = 0; kc < 4; ++kc) {
        int slot = ((kh * 4 + kc) * 2 + lh) ^ ksalt;
        kfr[kc] = *(const bf16x8*)(Kb + (size_t)krow * 256 + slot * 16);
      }
      __builtin_amdgcn_s_setprio(1);
#pragma unroll
      for (int kc = 0; kc < 4; ++kc)
        sa = __builtin_amdgcn_mfma_f32_32x32x16_bf16(kfr[kc], qf[kh * 4 + kc], sa, 0, 0, 0);
      __builtin_amdgcn_s_setprio(0);
    }

    float p[16];
#pragma unroll
    for (int i = 0; i < 16; ++i) {
      p[i] = __expf(sa[i]);
      l_lane += p[i];
    }
    unsigned wv[8], xv[8];
#pragma unroll
    for (int j = 0; j < 8; ++j) wv[j] = cvt_pk_bf16(p[2 * j], p[2 * j + 1]);
#pragma unroll
    for (int j = 0; j < 8; ++j) xv[j] = (unsigned)__shfl_xor((int)wv[j], 32, 64);
    int4 pa0i = lh ? (int4){(int)xv[2], (int)xv[3], (int)wv[2], (int)wv[3]}
                   : (int4){(int)wv[0], (int)wv[1], (int)xv[0], (int)xv[1]};
    int4 pa1i = lh ? (int4){(int)xv[6], (int)xv[7], (int)wv[6], (int)wv[7]}
                   : (int4){(int)wv[4], (int)wv[5], (int)xv[4], (int)xv[5]};
    bf16x8 pa[2] = {*(bf16x8*)&pa0i, *(bf16x8*)&pa1i};

#pragma unroll
    for (int dn = 0; dn < 2; ++dn) {
      int d = dn * 32 + l31;
      int dsalt = (d ^ (d >> 3)) & 7;
      bf16x8 vf[2];
#pragma unroll
      for (int kc = 0; kc < 2; ++kc) {
        int slot = (wk * 4 + kc * 2 + lh) ^ dsalt;
        vf[kc] = *(const bf16x8*)(Vb + (size_t)d * 128 + slot * 16);
      }
      __builtin_amdgcn_s_setprio(1);
#pragma unroll
      for (int kc = 0; kc < 2; ++kc)
        O[dn] = __builtin_amdgcn_mfma_f32_32x32x16_bf16(pa[kc], vf[kc], O[dn], 0, 0, 0);
      __builtin_amdgcn_s_setprio(0);
    }

    if (it < 15) {
      char* Kw = (char*)(KtS[cur ^ 1]);
      char* Vw = (char*)(VtS[cur ^ 1]);
#pragma unroll
      for (int c = 0; c < 4; ++c) {
        int u = c * 256 + t, r = u >> 4, s = u & 15;
        *(bf16x8*)(Kw + (size_t)r * 256 + (s ^ ((r ^ (r >> 3)) & 7)) * 16) = kreg[c];
      }
#pragma unroll
      for (int c = 0; c < 2; ++c) {
        int u = c * 256 + t, r = u >> 3, s = u & 7;
        *(bf16x8*)(Vw + (size_t)r * 128 + (s ^ ((r ^ (r >> 3)) & 7)) * 16) = vreg[c];
      }
      if (it < 14) {
        const char* kg = kgbase + (size_t)(it + 2) * 64 * 256;
#pragma unroll
        for (int c = 0; c < 4; ++c) {
          int u = c * 256 + t;
          kreg[c] = *(const bf16x8*)(kg + (size_t)(u >> 4) * 256 + (u & 15) * 16);
        }
        const char* vg = vgbase + (size_t)(it + 2) * 64 * 2;
#pragma unroll
        for (int c = 0; c < 2; ++c) {
          int u = c * 256 + t;
          vreg[c] = *(const bf16x8*)(vg + (size_t)(u >> 3) * 2048 + (u & 7) * 16);
        }
      }
    }
    __syncthreads();
  }

  l_lane += __shfl_xor(l_lane, 32, 64);
  if (lh == 0) Lsum[wk][wq][l31] = l_lane;
  float* scratch = (float*)KtS[0];
  if (wk == 1) {
#pragma unroll
    for (int i = 0; i < 16; ++i) {
      int qr = wq * 32 + ((i & 3) + 8 * (i >> 2) + 4 * lh);
      scratch[qr * 64 + l31] = O[0][i];
      scratch[qr * 64 + 32 + l31] = O[1][i];
    }
  }
  __syncthreads();
  if (wk == 0) {
#pragma unroll
    for (int i = 0; i < 16; ++i) {
      int cr = (i & 3) + 8 * (i >> 2) + 4 * lh;
      int qr = wq * 32 + cr;
      float inv = 1.0f / (Lsum[0][wq][cr] + Lsum[1][wq][cr]);
      float* op = out + ((size_t)b * 1024 + q0 + qr) * 512 + h * 64;
      op[l31] = (O[0][i] + scratch[qr * 64 + l31]) * inv;
      op[32 + l31] = (O[1][i] + scratch[qr * 64 + 32 + l31]) * inv;
    }
  }
}

extern "C" void kernel_launch(void* const* d_in, const int* in_sizes, int n_in,
                              void* d_out, int out_size, void* d_ws, size_t ws_size,
                              hipStream_t stream) {
  const float* x = (const float*)d_in[0];
  const float* W = (const float*)d_in[1];
  const float* bias = (const float*)d_in[2];
  float* out = (float*)d_out;

  UST* ws = (UST*)d_ws;
  UST* xbf  = ws;                       // 4096*512
  UST* WT   = xbf + 4096 * 512;         // 1536*512
  UST* qext = WT + 1536 * 512;          // 32*1024*128
  UST* kext = qext + 32 * 1024 * 128;   // 32*1024*128
  UST* vT   = kext + 32 * 1024 * 128;   // 32*64*1024

  k_setup<<<dim3(2368), dim3(256), 0, stream>>>(x, xbf, kext, W, WT);
  k_proj<<<dim3(32, 24), dim3(256), 0, stream>>>(xbf, WT, bias, qext, kext, vT);
  k_attn<<<dim3(512), dim3(256), 0, stream>>>(qext, kext, vT, out);
}

// Round 21
// 53.975 us; speedup vs baseline: 1.0150x; 1.0150x over previous
//
#include <hip/hip_runtime.h>

typedef unsigned short UST;
typedef __attribute__((ext_vector_type(8))) __bf16 bf16x8;
typedef __attribute__((ext_vector_type(4))) float f32x4;
typedef __attribute__((ext_vector_type(16))) float f32x16;

#define NB 4
#define NH 8
#define LSEQ 1024
#define DMODEL 512
#define DH 64

__device__ __forceinline__ UST f2bf(float f) {
  union { float f; unsigned u; } v; v.f = f;
  unsigned u = v.u;
  return (UST)((u + 0x7FFFu + ((u >> 16) & 1u)) >> 16);
}
__device__ __forceinline__ float bf2f(UST h) {
  union { unsigned u; float f; } v; v.u = ((unsigned)h) << 16;
  return v.f;
}
__device__ __forceinline__ unsigned cvt_pk_bf16(float lo, float hi) {
  unsigned r;
  asm volatile("v_cvt_pk_bf16_f32 %0, %1, %2" : "=v"(r) : "v"(lo), "v"(hi));
  return r;
}

// ---------------- kernel 1: fused setup (R17/R19-verified, best config) ----------------
// blocks 0..2047:    x fp32 -> bf16
// blocks 2048..6143: beta fill of kext cols 64..127 (per-bh compute: R20's dedup
//                    variant measured neutral-to-negative due to strided copies)
// blocks 6144..6335: W transpose -> WT bf16 (24x8 tiles)
__global__ void k_setup(const float* __restrict__ x, UST* __restrict__ xbf,
                        UST* __restrict__ kext,
                        const float* __restrict__ W, UST* __restrict__ WT) {
  __shared__ float tile[64][65];
  int bid = blockIdx.x;
  if (bid < 2048) {
    int i = bid * 256 + threadIdx.x;   // 2097152/4 elements
    float4 v = ((const float4*)x)[i];
    ushort4 o;
    o.x = f2bf(v.x); o.y = f2bf(v.y); o.z = f2bf(v.z); o.w = f2bf(v.w);
    ((ushort4*)xbf)[i] = o;
  } else if (bid < 6144) {
    int gid = (bid - 2048) * 256 + threadIdx.x;  // 32*1024*32
    int j = gid & 31;
    int l = (gid >> 5) & 1023;
    int bh = gid >> 15;
    float dd = exp2f((float)(-2 * j) * 0.20762050593046f);
    float ang = (float)l * dd;
    float s = __sinf(ang), c = __cosf(ang);
    UST* kp = kext + ((size_t)bh * 1024 + l) * 128;
    kp[64 + j] = f2bf(c);
    kp[96 + j] = f2bf(s);
  } else {
    int tid = bid - 6144;               // 0..191 = 24 x 8 tiles
    int n0 = (tid % 24) * 64;           // over 1536
    int k0 = (tid / 24) * 64;           // over 512
    int tx = threadIdx.x & 63, ty = threadIdx.x >> 6;  // ty 0..3
#pragma unroll
    for (int i = 0; i < 16; ++i) {
      int k = ty + i * 4;
      tile[k][tx] = W[(size_t)(k0 + k) * 1536 + n0 + tx];
    }
    __syncthreads();
#pragma unroll
    for (int i = 0; i < 16; ++i) {
      int n = ty + i * 4;
      WT[(size_t)(n0 + n) * 512 + k0 + tx] = f2bf(tile[tx][n]);
    }
  }
}

// ---------------- kernel 3: projection GEMM + scatter + fused alpha (R17) ----------
__global__ __launch_bounds__(256) void k_proj(
    const UST* __restrict__ xbf, const UST* __restrict__ WT, const float* __restrict__ bias,
    UST* __restrict__ qext, UST* __restrict__ kext, UST* __restrict__ vT) {
  int m0 = blockIdx.x * 128;  // token tile
  int n0 = blockIdx.y * 64;   // out-col tile
  int t = threadIdx.x;
  int lane = t & 63, w = t >> 6;
  int wr = w >> 1, wc = w & 1;
  int g = lane >> 4, c16 = lane & 15;

  __shared__ UST AtS[2][128 * 64];  // 2 x 16KB
  __shared__ UST BtS[2][64 * 64];   // 2 x 8KB

  const char* Ag = (const char*)(xbf + (size_t)m0 * 512);  // row stride 1024B
  const char* Bg = (const char*)(WT + (size_t)n0 * 512);   // row stride 1024B

  bf16x8 areg[4], breg[2];
#pragma unroll
  for (int c = 0; c < 4; ++c) {
    int u = c * 256 + t, r = u >> 3, s = u & 7;
    areg[c] = *(const bf16x8*)(Ag + (size_t)r * 1024 + s * 16);
  }
#pragma unroll
  for (int c = 0; c < 2; ++c) {
    int u = c * 256 + t, r = u >> 3, s = u & 7;
    breg[c] = *(const bf16x8*)(Bg + (size_t)r * 1024 + s * 16);
  }
#pragma unroll
  for (int c = 0; c < 4; ++c) {
    int u = c * 256 + t, r = u >> 3, s = u & 7;
    *(bf16x8*)((char*)AtS[0] + (size_t)r * 128 + (s ^ (r & 7)) * 16) = areg[c];
  }
#pragma unroll
  for (int c = 0; c < 2; ++c) {
    int u = c * 256 + t, r = u >> 3, s = u & 7;
    *(bf16x8*)((char*)BtS[0] + (size_t)r * 128 + (s ^ (r & 7)) * 16) = breg[c];
  }
#pragma unroll
  for (int c = 0; c < 4; ++c) {
    int u = c * 256 + t, r = u >> 3, s = u & 7;
    areg[c] = *(const bf16x8*)(Ag + (size_t)r * 1024 + 128 + s * 16);
  }
#pragma unroll
  for (int c = 0; c < 2; ++c) {
    int u = c * 256 + t, r = u >> 3, s = u & 7;
    breg[c] = *(const bf16x8*)(Bg + (size_t)r * 1024 + 128 + s * 16);
  }
  __syncthreads();

  f32x4 acc[4][2] = {};
  for (int it = 0; it < 8; ++it) {
    int cur = it & 1;
    const char* Ab = (const char*)(AtS[cur]);
    const char* Bb = (const char*)(BtS[cur]);

#pragma unroll
    for (int kf = 0; kf < 2; ++kf) {
      bf16x8 af[4], bfr[2];
#pragma unroll
      for (int rf = 0; rf < 4; ++rf) {
        int r = wr * 64 + rf * 16 + c16;
        int s = (kf * 4 + g) ^ (r & 7);
        af[rf] = *(const bf16x8*)(Ab + (size_t)r * 128 + s * 16);
      }
#pragma unroll
      for (int cf = 0; cf < 2; ++cf) {
        int r = wc * 32 + cf * 16 + c16;
        int s = (kf * 4 + g) ^ (r & 7);
        bfr[cf] = *(const bf16x8*)(Bb + (size_t)r * 128 + s * 16);
      }
      __builtin_amdgcn_s_setprio(1);
#pragma unroll
      for (int rf = 0; rf < 4; ++rf)
#pragma unroll
        for (int cf = 0; cf < 2; ++cf)
          acc[rf][cf] = __builtin_amdgcn_mfma_f32_16x16x32_bf16(af[rf], bfr[cf], acc[rf][cf], 0, 0, 0);
      __builtin_amdgcn_s_setprio(0);
    }

    if (it < 7) {
      char* Aw = (char*)(AtS[cur ^ 1]);
      char* Bw = (char*)(BtS[cur ^ 1]);
#pragma unroll
      for (int c = 0; c < 4; ++c) {
        int u = c * 256 + t, r = u >> 3, s = u & 7;
        *(bf16x8*)(Aw + (size_t)r * 128 + (s ^ (r & 7)) * 16) = areg[c];
      }
#pragma unroll
      for (int c = 0; c < 2; ++c) {
        int u = c * 256 + t, r = u >> 3, s = u & 7;
        *(bf16x8*)(Bw + (size_t)r * 128 + (s ^ (r & 7)) * 16) = breg[c];
      }
      if (it < 6) {
        size_t cb = (size_t)(it + 2) * 128;
#pragma unroll
        for (int c = 0; c < 4; ++c) {
          int u = c * 256 + t, r = u >> 3, s = u & 7;
          areg[c] = *(const bf16x8*)(Ag + (size_t)r * 1024 + cb + s * 16);
        }
#pragma unroll
        for (int c = 0; c < 2; ++c) {
          int u = c * 256 + t, r = u >> 3, s = u & 7;
          breg[c] = *(const bf16x8*)(Bg + (size_t)r * 1024 + cb + s * 16);
        }
      }
    }
    __syncthreads();
  }

  bool doalpha = (blockIdx.y % 3 == 0);   // block-uniform
  UST* stash = AtS[0];

#pragma unroll
  for (int rf = 0; rf < 4; ++rf) {
#pragma unroll
    for (int cf = 0; cf < 2; ++cf) {
      int c = n0 + wc * 32 + cf * 16 + c16;
      int h = c / 192, rem = c % 192;
      float bv = bias[c];
#pragma unroll
      for (int r = 0; r < 4; ++r) {
        int row = m0 + wr * 64 + rf * 16 + g * 4 + r;
        int bidx = row >> 10, ltok = row & 1023;
        int bh = bidx * 8 + h;
        float val = acc[rf][cf][r] + bv;
        if (rem < 64) {
          UST qv = f2bf(val * 0.125f);
          qext[((size_t)bh * 1024 + ltok) * 128 + rem] = qv;
          if (doalpha)
            stash[(size_t)(row - m0) * 64 + rem] = qv;
        } else if (rem < 128)
          kext[((size_t)bh * 1024 + ltok) * 128 + (rem - 64)] = f2bf(val);
        else
          vT[((size_t)bh * 64 + (rem - 128)) * 1024 + ltok] = f2bf(val);
      }
    }
  }

  if (doalpha) {
    __syncthreads();
    int hh = blockIdx.y / 3;
    int rr = t >> 1;
    int row = m0 + rr;
    int bidx = row >> 10, ltok = row & 1023;
    int bh = bidx * 8 + hh;
    UST* qp = qext + ((size_t)bh * 1024 + ltok) * 128;
#pragma unroll
    for (int i = 0; i < 16; ++i) {
      int j = (t & 1) * 16 + i;
      float dd = exp2f((float)(-2 * j) * 0.20762050593046f);
      float ang = (float)ltok * dd;
      float s = __sinf(ang), c = __cosf(ang);
      float qs = bf2f(stash[(size_t)rr * 64 + j]);
      float qc = bf2f(stash[(size_t)rr * 64 + 32 + j]);
      qp[64 + j] = f2bf(qs * s + qc * c);
      qp[96 + j] = f2bf(qc * s - qs * c);
    }
  }
}

// ---------------- kernel 5: fused flash attention (R17/R19-verified, unchanged) ------
__global__ __launch_bounds__(256) void k_attn(
    const UST* __restrict__ qext, const UST* __restrict__ kext,
    const UST* __restrict__ vT, float* __restrict__ out) {
  int blk = ((blockIdx.x & 7) << 6) | (blockIdx.x >> 3);  // XCD-contiguous bh ranges
  int qt = blk & 15, bh = blk >> 4;
  int b = bh >> 3, h = bh & 7;
  int q0 = qt * 64;
  int t = threadIdx.x;
  int lane = t & 63, w = t >> 6;
  int l31 = lane & 31, lh = lane >> 5;
  int wq = w >> 1, wk = w & 1;

  __shared__ UST KtS[2][64 * 128];   // 2 x 16KB
  __shared__ UST VtS[2][64 * 64];    // 2 x 8KB
  __shared__ float Lsum[2][2][32];   // [wk][wq][row]

  const UST* qbase = qext + ((size_t)bh * 1024 + q0 + wq * 32 + l31) * 128 + lh * 8;
  bf16x8 qf[8];
#pragma unroll
  for (int c = 0; c < 8; ++c) qf[c] = *(const bf16x8*)&qbase[c * 16];

  const char* kgbase = (const char*)(kext + (size_t)bh * 1024 * 128);
  const char* vgbase = (const char*)(vT + (size_t)bh * 64 * 1024);

  f32x16 O[2] = {};
  float l_lane = 0.f;

  bf16x8 kreg[4], vreg[2];
#pragma unroll
  for (int c = 0; c < 4; ++c) {
    int u = c * 256 + t;
    kreg[c] = *(const bf16x8*)(kgbase + (size_t)(u >> 4) * 256 + (u & 15) * 16);
  }
#pragma unroll
  for (int c = 0; c < 2; ++c) {
    int u = c * 256 + t;
    vreg[c] = *(const bf16x8*)(vgbase + (size_t)(u >> 3) * 2048 + (u & 7) * 16);
  }
#pragma unroll
  for (int c = 0; c < 4; ++c) {
    int u = c * 256 + t, r = u >> 4, s = u & 15;
    *(bf16x8*)((char*)KtS[0] + (size_t)r * 256 + (s ^ ((r ^ (r >> 3)) & 7)) * 16) = kreg[c];
  }
#pragma unroll
  for (int c = 0; c < 2; ++c) {
    int u = c * 256 + t, r = u >> 3, s = u & 7;
    *(bf16x8*)((char*)VtS[0] + (size_t)r * 128 + (s ^ ((r ^ (r >> 3)) & 7)) * 16) = vreg[c];
  }
#pragma unroll
  for (int c = 0; c < 4; ++c) {
    int u = c * 256 + t;
    kreg[c] = *(const bf16x8*)(kgbase + 64 * 256 + (size_t)(u >> 4) * 256 + (u & 15) * 16);
  }
#pragma unroll
  for (int c = 0; c < 2; ++c) {
    int u = c * 256 + t;
    vreg[c] = *(const bf16x8*)(vgbase + 64 * 2 + (size_t)(u >> 3) * 2048 + (u & 7) * 16);
  }
  __syncthreads();

  int krow = wk * 32 + l31;
  int ksalt = (krow ^ (krow >> 3)) & 7;

  for (int it = 0; it < 16; ++it) {
    int cur = it & 1;
    const char* Kb = (const char*)(KtS[cur]);
    const char* Vb = (const char*)(VtS[cur]);

    f32x16 sa = {};
#pragma unroll
    for (int kh = 0; kh < 2; ++kh) {
      bf16x8 kfr[4];
#pragma unroll
      for (int kc = 0; kc < 4; ++kc) {
        int slot = ((kh * 4 + kc) * 2 + lh) ^ ksalt;
        kfr[kc] = *(const bf16x8*)(Kb + (size_t)krow * 256 + slot * 16);
      }
      __builtin_amdgcn_s_setprio(1);
#pragma unroll
      for (int kc = 0; kc < 4; ++kc)
        sa = __builtin_amdgcn_mfma_f32_32x32x16_bf16(kfr[kc], qf[kh * 4 + kc], sa, 0, 0, 0);
      __builtin_amdgcn_s_setprio(0);
    }

    float p[16];
#pragma unroll
    for (int i = 0; i < 16; ++i) {
      p[i] = __expf(sa[i]);
      l_lane += p[i];
    }
    unsigned wv[8], xv[8];
#pragma unroll
    for (int j = 0; j < 8; ++j) wv[j] = cvt_pk_bf16(p[2 * j], p[2 * j + 1]);
#pragma unroll
    for (int j = 0; j < 8; ++j) xv[j] = (unsigned)__shfl_xor((int)wv[j], 32, 64);
    int4 pa0i = lh ? (int4){(int)xv[2], (int)xv[3], (int)wv[2], (int)wv[3]}
                   : (int4){(int)wv[0], (int)wv[1], (int)xv[0], (int)xv[1]};
    int4 pa1i = lh ? (int4){(int)xv[6], (int)xv[7], (int)wv[6], (int)wv[7]}
                   : (int4){(int)wv[4], (int)wv[5], (int)xv[4], (int)xv[5]};
    bf16x8 pa[2] = {*(bf16x8*)&pa0i, *(bf16x8*)&pa1i};

#pragma unroll
    for (int dn = 0; dn < 2; ++dn) {
      int d = dn * 32 + l31;
      int dsalt = (d ^ (d >> 3)) & 7;
      bf16x8 vf[2];
#pragma unroll
      for (int kc = 0; kc < 2; ++kc) {
        int slot = (wk * 4 + kc * 2 + lh) ^ dsalt;
        vf[kc] = *(const bf16x8*)(Vb + (size_t)d * 128 + slot * 16);
      }
      __builtin_amdgcn_s_setprio(1);
#pragma unroll
      for (int kc = 0; kc < 2; ++kc)
        O[dn] = __builtin_amdgcn_mfma_f32_32x32x16_bf16(pa[kc], vf[kc], O[dn], 0, 0, 0);
      __builtin_amdgcn_s_setprio(0);
    }

    if (it < 15) {
      char* Kw = (char*)(KtS[cur ^ 1]);
      char* Vw = (char*)(VtS[cur ^ 1]);
#pragma unroll
      for (int c = 0; c < 4; ++c) {
        int u = c * 256 + t, r = u >> 4, s = u & 15;
        *(bf16x8*)(Kw + (size_t)r * 256 + (s ^ ((r ^ (r >> 3)) & 7)) * 16) = kreg[c];
      }
#pragma unroll
      for (int c = 0; c < 2; ++c) {
        int u = c * 256 + t, r = u >> 3, s = u & 7;
        *(bf16x8*)(Vw + (size_t)r * 128 + (s ^ ((r ^ (r >> 3)) & 7)) * 16) = vreg[c];
      }
      if (it < 14) {
        const char* kg = kgbase + (size_t)(it + 2) * 64 * 256;
#pragma unroll
        for (int c = 0; c < 4; ++c) {
          int u = c * 256 + t;
          kreg[c] = *(const bf16x8*)(kg + (size_t)(u >> 4) * 256 + (u & 15) * 16);
        }
        const char* vg = vgbase + (size_t)(it + 2) * 64 * 2;
#pragma unroll
        for (int c = 0; c < 2; ++c) {
          int u = c * 256 + t;
          vreg[c] = *(const bf16x8*)(vg + (size_t)(u >> 3) * 2048 + (u & 7) * 16);
        }
      }
    }
    __syncthreads();
  }

  l_lane += __shfl_xor(l_lane, 32, 64);
  if (lh == 0) Lsum[wk][wq][l31] = l_lane;
  float* scratch = (float*)KtS[0];
  if (wk == 1) {
#pragma unroll
    for (int i = 0; i < 16; ++i) {
      int qr = wq * 32 + ((i & 3) + 8 * (i >> 2) + 4 * lh);
      scratch[qr * 64 + l31] = O[0][i];
      scratch[qr * 64 + 32 + l31] = O[1][i];
    }
  }
  __syncthreads();
  if (wk == 0) {
#pragma unroll
    for (int i = 0; i < 16; ++i) {
      int cr = (i & 3) + 8 * (i >> 2) + 4 * lh;
      int qr = wq * 32 + cr;
      float inv = 1.0f / (Lsum[0][wq][cr] + Lsum[1][wq][cr]);
      float* op = out + ((size_t)b * 1024 + q0 + qr) * 512 + h * 64;
      op[l31] = (O[0][i] + scratch[qr * 64 + l31]) * inv;
      op[32 + l31] = (O[1][i] + scratch[qr * 64 + 32 + l31]) * inv;
    }
  }
}

extern "C" void kernel_launch(void* const* d_in, const int* in_sizes, int n_in,
                              void* d_out, int out_size, void* d_ws, size_t ws_size,
                              hipStream_t stream) {
  const float* x = (const float*)d_in[0];
  const float* W = (const float*)d_in[1];
  const float* bias = (const float*)d_in[2];
  float* out = (float*)d_out;

  UST* ws = (UST*)d_ws;
  UST* xbf  = ws;                       // 4096*512
  UST* WT   = xbf + 4096 * 512;         // 1536*512
  UST* qext = WT + 1536 * 512;          // 32*1024*128
  UST* kext = qext + 32 * 1024 * 128;   // 32*1024*128
  UST* vT   = kext + 32 * 1024 * 128;   // 32*64*1024

  k_setup<<<dim3(6336), dim3(256), 0, stream>>>(x, xbf, kext, W, WT);
  k_proj<<<dim3(32, 24), dim3(256), 0, stream>>>(xbf, WT, bias, qext, kext, vT);
  k_attn<<<dim3(512), dim3(256), 0, stream>>>(qext, kext, vT, out);
}